// Round 5
// baseline (1694.794 us; speedup 1.0000x reference)
//
#include <hip/hip_runtime.h>

#define NTRIAL 8
#define NNEUR 100
#define NTT 256
#define NT_FULL 300
#define NTAU 50
#define NLAT 8
#define NPAD 44
#define LRATE 0.2f
#define JITTER 0.001f
#define NMAT 64            // NTRIAL*NLAT batched 256x256 matrices
#define NSLOT 136          // 16*17/2 lower 16x16 blocks
#define SPITCH 260         // floats per block slot
#define NBLKF 35360        // NSLOT*SPITCH
#define NBLKF4 8840        // float4 count

__device__ __forceinline__ int bslot(int I, int J){ return ((I*(I+1))>>1) + J; }
// scalar float index of element (row i, col j) within one 260-float tile slot
__device__ __forceinline__ int rcs(int i, int j){
    return i*16 + ((((j>>2) + (i>>2))&3)<<2) + (j&3);
}
__device__ __forceinline__ int eidx(int I, int J, int i, int j){
    return bslot(I,J)*SPITCH + rcs(i,j);
}
// float4 index of chunk q (cols 4q..4q+3) of row i within a 65-f4 tile
__device__ __forceinline__ int rc4(int i, int q){ return i*4 + ((q + (i>>2))&3); }
__device__ __forceinline__ int f4idx(int I, int J, int i, int q){
    return bslot(I,J)*65 + rc4(i,q);
}
#define DOT4(u,v) (u.x*v.x + u.y*v.y + u.z*v.z + u.w*v.w)

// acc += rowsA(ti..ti+3) . rowsB(tj..tj+3)  (16-wide dots, both row-chunk-swizzled tiles)
__device__ __forceinline__ void gemmRR(const float4* A, int baseA, const float4* B, int baseB,
                                       int ti, int tj, float acc[4][4]){
    #pragma unroll
    for (int kc = 0; kc < 4; ++kc){
        float4 a0 = A[baseA + rc4(ti+0,kc)];
        float4 a1 = A[baseA + rc4(ti+1,kc)];
        float4 a2 = A[baseA + rc4(ti+2,kc)];
        float4 a3 = A[baseA + rc4(ti+3,kc)];
        float4 b0 = B[baseB + rc4(tj+0,kc)];
        float4 b1 = B[baseB + rc4(tj+1,kc)];
        float4 b2 = B[baseB + rc4(tj+2,kc)];
        float4 b3 = B[baseB + rc4(tj+3,kc)];
        acc[0][0]+=DOT4(a0,b0); acc[0][1]+=DOT4(a0,b1); acc[0][2]+=DOT4(a0,b2); acc[0][3]+=DOT4(a0,b3);
        acc[1][0]+=DOT4(a1,b0); acc[1][1]+=DOT4(a1,b1); acc[1][2]+=DOT4(a1,b2); acc[1][3]+=DOT4(a1,b3);
        acc[2][0]+=DOT4(a2,b0); acc[2][1]+=DOT4(a2,b1); acc[2][2]+=DOT4(a2,b2); acc[2][3]+=DOT4(a2,b3);
        acc[3][0]+=DOT4(a3,b0); acc[3][1]+=DOT4(a3,b1); acc[3][2]+=DOT4(a3,b2); acc[3][3]+=DOT4(a3,b3);
    }
}

// ---------------- init ----------------
__global__ void k_zero(float* mu, float* scal){
    int i = blockIdx.x*256 + threadIdx.x;
    if (i < 16384) mu[i] = 0.f;
    if (i < 64) scal[i] = 0.f;
}

__global__ void k_transpose(const float* __restrict__ kern, float* __restrict__ kt){
    int idx = blockIdx.x*256 + threadIdx.x;
    if (idx >= NNEUR*NTAU*NNEUR) return;
    int i = idx/(NTAU*NNEUR); int rem = idx%(NTAU*NNEUR);
    int tau = rem/NNEUR; int j = rem%NNEUR;
    kt[((size_t)i*NNEUR + j)*NTAU + tau] = kern[idx];
}

// ---------------- conv + readout contraction ----------------
__global__ __launch_bounds__(256) void k_conv_weights(const float* __restrict__ raw,
                                                      const float* __restrict__ kt,
                                                      const float* __restrict__ readout,
                                                      float* __restrict__ W){
    int b = blockIdx.x; int m = b / NNEUR; int j = b % NNEUR; int t = threadIdx.x;
    __shared__ float ro[NNEUR*NLAT];
    __shared__ float raw_s[10][NT_FULL];
    __shared__ float kern_s[10][NTAU];
    for (int idx = t; idx < NNEUR*NLAT; idx += 256) ro[idx] = readout[idx];
    float acc[NLAT];
    #pragma unroll
    for (int l = 0; l < NLAT; ++l) acc[l] = 0.f;
    int tmax = min(NTAU, t + NPAD);
    for (int c = 0; c < 10; ++c){
        __syncthreads();
        for (int idx = t; idx < 10*NT_FULL; idx += 256){
            int ii = idx / NT_FULL, tt = idx % NT_FULL;
            raw_s[ii][tt] = raw[((size_t)m*NNEUR + c*10 + ii)*NT_FULL + tt];
        }
        for (int idx = t; idx < 10*NTAU; idx += 256){
            int ii = idx / NTAU, tau = idx % NTAU;
            kern_s[ii][tau] = kt[((size_t)(c*10 + ii)*NNEUR + j)*NTAU + tau];
        }
        __syncthreads();
        for (int ii = 0; ii < 10; ++ii){
            float g = 0.f;
            const float* kr = kern_s[ii];
            const float* rr = raw_s[ii];
            for (int tau = 1; tau <= tmax; ++tau) g += kr[tau-1] * rr[t + NPAD - tau];
            if (fabsf(g) < 1e-5f) g = 0.f;   // ZERO_THRESH before readout contraction
            const float* rop = &ro[(c*10 + ii)*NLAT];
            #pragma unroll
            for (int l = 0; l < NLAT; ++l) acc[l] += rop[l]*g;
        }
    }
    #pragma unroll
    for (int l = 0; l < NLAT; ++l) W[(((size_t)b)*NLAT + l)*NTT + t] = acc[l];
}

// ---------------- lambda / grad-partials / w2l-partials (reads W exactly once) ----------------
// grid: 64 = (m 0..7) x (chunk 0..7). Writes partial slices; k_fact sums them.
__global__ __launch_bounds__(256) void k_grad2(const float* __restrict__ W, const float* __restrict__ Y,
                                               const float* __restrict__ bias_p,
                                               const float* __restrict__ muIn, const float* __restrict__ diagIn,
                                               float* __restrict__ gradPart, float* __restrict__ w2lPart,
                                               float* __restrict__ lambd, float* __restrict__ scal,
                                               int it0, int it4){
    int blk = blockIdx.x; int m = blk >> 3; int chunk = blk & 7;
    int n0 = chunk*12 + (chunk < 4 ? chunk : 4);
    int cnt = 12 + (chunk < 4 ? 1 : 0);
    int t = threadIdx.x;
    __shared__ float r1[256], r2[256];
    float mul[NLAT], dhl[NLAT];
    #pragma unroll
    for (int l = 0; l < NLAT; ++l){
        mul[l] = muIn[((size_t)(m*NLAT + l))*NTT + t];
        dhl[l] = it0 ? (1.0f + JITTER) : (-diagIn[((size_t)(m*NLAT + l))*NTT + t]);
    }
    float bias = bias_p[0];
    float ga[NLAT], wa[NLAT];
    #pragma unroll
    for (int l = 0; l < NLAT; ++l){ ga[l] = 0.f; wa[l] = 0.f; }
    float yl = 0.f, ls = 0.f;
    for (int n = n0; n < n0 + cnt; ++n){
        size_t base = (((size_t)(m*NNEUR + n))*NLAT)*NTT + t;
        float wl[NLAT];
        float ll = bias, q = 0.f;
        #pragma unroll
        for (int l = 0; l < NLAT; ++l){
            float w = W[base + (size_t)l*NTT];
            wl[l] = w;
            ll += w * mul[l];
            q  += w * w * dhl[l];
        }
        float lam = expf(ll + 0.5f*q);
        float yv = Y[((size_t)(m*NNEUR + n))*NTT + t];
        float d = yv - lam;
        #pragma unroll
        for (int l = 0; l < NLAT; ++l){ ga[l] += wl[l]*d; wa[l] += wl[l]*wl[l]*lam; }
        if (it4){
            lambd[((size_t)(m*NNEUR + n))*NTT + t] = lam;
            yl += yv * ll; ls += lam;
        }
    }
    #pragma unroll
    for (int l = 0; l < NLAT; ++l){
        gradPart[((size_t)((chunk<<6) + m*NLAT + l))*NTT + t] = ga[l];
        w2lPart [((size_t)((chunk<<6) + m*NLAT + l))*NTT + t] = wa[l];
    }
    if (it4){
        r1[t] = yl; r2[t] = ls;
        __syncthreads();
        for (int s = 128; s > 0; s >>= 1){ if (t < s){ r1[t]+=r1[t+s]; r2[t]+=r2[t+s]; } __syncthreads(); }
        if (t == 0){ atomicAdd(&scal[0], r1[0]); atomicAdd(&scal[1], r2[0]); }
    }
}

// ============ fused blocked Cholesky + IN-LOOP blocked triangular inverse ============
// MODE 0: 1 block. In Kin+jitter. Out Sblk (blocked X^T), scal[20]=logdet(K').
// MODE 1: NMAT blocks. Prologue sums grad/w2l partials + mk; A = invK + diag(w2l);
//         out: diagOut, muOut = muIn + LR*A^-1 grad, loss atomics.
template<int MODE>
__global__ __launch_bounds__(512) void k_fact(
    const float* __restrict__ Kin,
    const float* __restrict__ invKb,
    const float* __restrict__ gradPart,
    const float* __restrict__ w2lPart,
    const float* __restrict__ muIn,
    float* __restrict__ muOut,
    float* __restrict__ diagOut,
    float* __restrict__ Sout,
    float* __restrict__ scal,
    int it4, int itSlot)
{
    __shared__ float4 P4[NBLKF4];      // 141,440 B blocked lower-tri matrix
    __shared__ float4 Bs4[1104];       //  17,664 B: 15 B-slots (0..3899) + gs(3900..4155) + w2ls(4156..4411)
    __shared__ float4 XinvL4[130];     //   2,080 B: double-buffered Xinv_pp (row-chunk-swizzled)
    __shared__ float dlog[256];        //   chol diag values (overlay: muown pre-chol)
    __shared__ float idg[16];
    float* P     = (float*)P4;
    float* Bsf   = (float*)Bs4;
    float* gs    = Bsf + 3900;
    float* w2ls  = Bsf + 4156;
    float* red   = Bsf;                // epilogue/prologue scratch (B-area dead then)
    float* zp    = Bsf + 512;
    float* muown = dlog;
    const int t = threadIdx.x;
    const int b = blockIdx.x;
    const int g = t>>4, gt = t&15;
    const int ti = (gt>>2)<<2, tj = (gt&3)<<2;
    const int lanebase = t & 48;       // base lane of this 16-group within its wave

    // ---------------- prologue ----------------
    if (MODE == 0){
        if (t < 256){
            int r = t, I = r>>4, i = r&15;
            for (int c = 0; c <= r; ++c)
                P[eidx(I, c>>4, i, c&15)] = Kin[r*256 + c] + ((c==r)?JITTER:0.f);
        }
        __syncthreads();
    } else {
        const float4* G4 = (const float4*)invKb;
        for (int e = t; e < NBLKF4; e += 512) P4[e] = G4[e];
        if (t < 256) muown[t] = muIn[(size_t)b*NTT + t];
        __syncthreads();
        if (t < 256){
            float gg = 0.f, ww = 0.f;
            #pragma unroll
            for (int c = 0; c < 8; ++c){
                gg += gradPart[((size_t)((c<<6) + b))*NTT + t];
                ww += w2lPart [((size_t)((c<<6) + b))*NTT + t];
            }
            int T = t>>4, tb = t&15;
            float mk = 0.f;
            for (int U = 0; U < 16; ++U){
                if (U <= T){
                    #pragma unroll
                    for (int u = 0; u < 16; ++u) mk += muown[U*16+u] * P[eidx(T,U,tb,u)];
                } else {
                    #pragma unroll
                    for (int u = 0; u < 16; ++u) mk += muown[U*16+u] * P[eidx(U,T,u,tb)];
                }
            }
            gs[t]   = gg - mk;
            w2ls[t] = ww;
            red[t]  = mk * muown[t];
        }
        if (it4){
            __syncthreads();
            for (int s = 128; s > 0; s >>= 1){ if (t < s) red[t] += red[t+s]; __syncthreads(); }
            if (t == 0) atomicAdd(&scal[2], red[0]);
        }
        __syncthreads();                    // all mk reads of P done
        if (t < 256) P[eidx(t>>4, t>>4, t&15, t&15)] += w2ls[t];
        __syncthreads();
    }

    // ---------------- fused chol + trinv: 17 A-phases, 16 B-phases ----------------
    for (int p = 0; p <= 16; ++p){
        const int r = p - 1;                       // S-multiply row
        // ======= PHASE A =======
        if (g == 31){
            if (p < 16){
                float x[16];
                if (p > 0){
                    // trailing update of (p,p) with column r
                    float acc[4][4];
                    #pragma unroll
                    for (int aa=0;aa<4;++aa){acc[aa][0]=0;acc[aa][1]=0;acc[aa][2]=0;acc[aa][3]=0;}
                    gemmRR(P4, bslot(p,r)*65, P4, bslot(p,r)*65, ti, tj, acc);
                    #pragma unroll
                    for (int aa = 0; aa < 4; ++aa){
                        int oi = f4idx(p,p,ti+aa,tj>>2);
                        float4 c = P4[oi];
                        c.x-=acc[aa][0]; c.y-=acc[aa][1]; c.z-=acc[aa][2]; c.w-=acc[aa][3];
                        P4[oi] = c;
                    }
                }
                // micro-chol of (p,p): lane gt holds row gt in x[]
                #pragma unroll
                for (int q = 0; q < 4; ++q){
                    float4 v = P4[f4idx(p,p,gt,q)];
                    x[4*q]=v.x; x[4*q+1]=v.y; x[4*q+2]=v.z; x[4*q+3]=v.w;
                }
                const int i = gt;
                #pragma unroll
                for (int k = 0; k < 16; ++k){
                    float piv = __shfl(x[k], lanebase + k, 64);
                    float d = sqrtf(piv);
                    float dinv = 1.f/d;
                    float lik = (i == k) ? d : x[k]*dinv;
                    if (i >= k) x[k] = lik;
                    #pragma unroll
                    for (int c = k+1; c < 16; ++c){
                        float lck = __shfl(x[k], lanebase + c, 64);
                        if (i >= c) x[c] -= lik*lck;
                    }
                    if (i == k){ idg[k] = dinv; dlog[p*16+k] = d; }
                }
                // micro-trinv: lane gt computes column gt of Xinv = L_pp^-1
                float col[16];
                #pragma unroll
                for (int ii = 0; ii < 16; ++ii){
                    float s = 0.f;
                    #pragma unroll
                    for (int k = 0; k < 16; ++k){
                        if (k < ii){
                            float lik = __shfl(x[k], lanebase + ii, 64);
                            s += lik * col[k];
                        }
                    }
                    float v = ((gt == ii) ? 1.f : -s) * idg[ii];
                    col[ii] = (gt <= ii) ? v : 0.f;
                }
                // S_pp row gt = column gt of Xinv  (S[a][b] = X[b][a])
                #pragma unroll
                for (int q = 0; q < 4; ++q)
                    P4[f4idx(p,p,gt,q)] = make_float4(col[4*q],col[4*q+1],col[4*q+2],col[4*q+3]);
                // XinvL[p&1] row i gets element (i, gt)
                float* XL = (float*)(XinvL4 + (p&1)*65);
                #pragma unroll
                for (int ii = 0; ii < 16; ++ii) XL[rcs(ii, gt)] = col[ii];
            }
        } else {
            int m16 = 16 - p;
            int ntrail = (p >= 1 && p < 16) ? ((m16*(m16+1))>>1) - 1 : 0;
            int nsm = (p >= 1) ? (p - 1) : 0;
            for (int id = g; id < ntrail + nsm; id += 31){
                if (id < ntrail){
                    int q = id + 1;
                    int di = (int)floorf((sqrtf(8.f*(float)q + 1.f) - 1.f)*0.5f);
                    while (((di+1)*(di+2))>>1 <= q) ++di;
                    while ((di*(di+1))>>1 > q) --di;
                    int dj = q - ((di*(di+1))>>1);
                    int I = p + di, J = p + dj;
                    float acc[4][4];
                    #pragma unroll
                    for (int aa=0;aa<4;++aa){acc[aa][0]=0;acc[aa][1]=0;acc[aa][2]=0;acc[aa][3]=0;}
                    gemmRR(P4, bslot(I,r)*65, P4, bslot(J,r)*65, ti, tj, acc);
                    #pragma unroll
                    for (int aa = 0; aa < 4; ++aa){
                        int oi = f4idx(I,J,ti+aa,tj>>2);
                        float4 c = P4[oi];
                        c.x-=acc[aa][0]; c.y-=acc[aa][1]; c.z-=acc[aa][2]; c.w-=acc[aa][3];
                        P4[oi] = c;
                    }
                } else {
                    // S-multiply for row r, column J:  S_rJ = -(B^T Xinv^T), rows x rows
                    int J = id - ntrail;
                    float acc[4][4];
                    #pragma unroll
                    for (int aa=0;aa<4;++aa){acc[aa][0]=0;acc[aa][1]=0;acc[aa][2]=0;acc[aa][3]=0;}
                    gemmRR(Bs4, J*65, XinvL4, (r&1)*65, ti, tj, acc);
                    #pragma unroll
                    for (int aa = 0; aa < 4; ++aa)
                        P4[f4idx(r,J,ti+aa,tj>>2)] =
                            make_float4(-acc[aa][0],-acc[aa][1],-acc[aa][2],-acc[aa][3]);
                }
            }
        }
        __syncthreads();
        if (p == 16) break;
        // ======= PHASE B =======
        if (g < 2*p){
            // B_pJ = sum_{K=J..p-1} L_pK X_KJ on group-pair (2J, 2J+1)
            int J = g>>1, half = g&1;
            float acc[4][4];
            #pragma unroll
            for (int aa=0;aa<4;++aa){acc[aa][0]=0;acc[aa][1]=0;acc[aa][2]=0;acc[aa][3]=0;}
            for (int K = J + half; K < p; K += 2)
                gemmRR(P4, bslot(p,K)*65, P4, bslot(K,J)*65, ti, tj, acc);
            #pragma unroll
            for (int aa = 0; aa < 4; ++aa){
                #pragma unroll
                for (int bb = 0; bb < 4; ++bb)
                    acc[aa][bb] += __shfl_xor(acc[aa][bb], 16, 64);
            }
            if (half == 0){
                float* BJ = Bsf + J*260;      // store B transposed: Bs[a][k] = B[k][a]
                #pragma unroll
                for (int aa = 0; aa < 4; ++aa)
                    #pragma unroll
                    for (int bb = 0; bb < 4; ++bb)
                        BJ[rcs(tj+bb, ti+aa)] = acc[aa][bb];
            }
        } else {
            // panel solve: L_Ip = A_Ip * Xinv_pp^T, one tile per group
            int I = p + 1 + (g - 2*p);
            if (I < 16){
                float acc[4][4];
                #pragma unroll
                for (int aa=0;aa<4;++aa){acc[aa][0]=0;acc[aa][1]=0;acc[aa][2]=0;acc[aa][3]=0;}
                gemmRR(P4, bslot(I,p)*65, XinvL4, (p&1)*65, ti, tj, acc);
                #pragma unroll
                for (int aa = 0; aa < 4; ++aa)
                    P4[f4idx(I,p,ti+aa,tj>>2)] =
                        make_float4(acc[aa][0],acc[aa][1],acc[aa][2],acc[aa][3]);
            }
        }
        __syncthreads();
    }

    // ---------------- epilogue ----------------
    if (MODE == 0){
        red[t] = (t < 256) ? 2.f*logf(dlog[t]) : 0.f;
        __syncthreads();
        for (int s = 128; s > 0; s >>= 1){ if (t < s) red[t] += red[t+s]; __syncthreads(); }
        if (t == 0) scal[20] = red[0];
        float4* SO = (float4*)Sout;
        for (int e = t; e < NBLKF4; e += 512) SO[e] = P4[e];
        return;
    } else {
        float dsum = 0.f;
        if (t < 256){
            const int J0 = t>>4, j0 = t&15;
            for (int I = J0; I < 16; ++I){
                #pragma unroll
                for (int q = 0; q < 4; ++q){
                    float4 v = P4[f4idx(I,J0,j0,q)];
                    dsum += v.x*v.x + v.y*v.y + v.z*v.z + v.w*v.w;
                }
            }
            diagOut[(size_t)b*NTT + t] = dsum;
            const int Ir = t>>4, rb = t&15;
            float z = 0.f;
            for (int J = 0; J <= Ir; ++J){
                #pragma unroll
                for (int j = 0; j < 16; ++j) z += P[eidx(Ir,J,j,rb)]*gs[J*16+j];
            }
            zp[t] = z;
        }
        __syncthreads();
        if (t < 256){
            const int J0 = t>>4, j0 = t&15;
            float u = 0.f;
            for (int I = J0; I < 16; ++I){
                #pragma unroll
                for (int q = 0; q < 4; ++q){
                    float4 v = P4[f4idx(I,J0,j0,q)];
                    const float* zz = &zp[I*16 + 4*q];
                    u += v.x*zz[0] + v.y*zz[1] + v.z*zz[2] + v.w*zz[3];
                }
            }
            muOut[(size_t)b*NTT + t] = muIn[(size_t)b*NTT + t] + LRATE*u;
            red[t]       = w2ls[t]*dsum;
            red[256 + t] = 2.f*logf(dlog[t]);
        }
        __syncthreads();
        for (int s = 128; s > 0; s >>= 1){
            if (t < s){ red[t] += red[t+s]; red[256+t] += red[256+t+s]; }
            __syncthreads();
        }
        if (t == 0){
            atomicAdd(&scal[8 + itSlot],  red[0] - 256.f);          // trace(invK * -A^-1)
            atomicAdd(&scal[24 + itSlot], -scal[20] - red[256]);    // logdet(invK) - logdet(A)
        }
    }
}

// ---------------- invKb = X^T X (blocked) ----------------
__global__ __launch_bounds__(256) void k_syrk(const float* __restrict__ S,
                                              float* __restrict__ invKb){
    int sidx = blockIdx.x;
    int I = (int)floorf((sqrtf(8.f*(float)sidx + 1.f) - 1.f)*0.5f);
    while (((I+1)*(I+2))>>1 <= sidx) ++I;
    while ((I*(I+1))>>1 > sidx) --I;
    int J = sidx - ((I*(I+1))>>1);
    int t = threadIdx.x; int i = t>>4, j = t&15;
    __shared__ float4 sA[64], sB[64];
    const float4* S4 = (const float4*)S;
    float s = 0.f;
    for (int R = I; R < 16; ++R){
        __syncthreads();
        if (t < 64) sA[t] = S4[bslot(R,I)*65 + t];
        else if (t < 128) sB[t-64] = S4[bslot(R,J)*65 + t-64];
        __syncthreads();
        #pragma unroll
        for (int q = 0; q < 4; ++q){
            float4 a = sA[rc4(i,q)];
            float4 c = sB[rc4(j,q)];
            s += a.x*c.x + a.y*c.y + a.z*c.z + a.w*c.w;
        }
    }
    invKb[eidx(I,J,i,j)] = s;
}

__global__ void k_loss(const float* __restrict__ scal, float* __restrict__ out_loss){
    // loss = sum(Y*ll) - sum(lam) - 0.5*muKmu - 0.5*trace + 0.5*logabs - nt
    out_loss[0] = scal[0] - scal[1] - 0.5f*scal[2] - 0.5f*scal[8+3] + 0.5f*scal[24+3] - 256.f;
}

__global__ void k_gather(const float* __restrict__ mu, const float* __restrict__ lambd, float* __restrict__ out){
    int idx = blockIdx.x*256 + threadIdx.x;
    if (idx < 16384) out[idx] = mu[idx];
    else if (idx < 16384 + 204800) out[idx] = lambd[idx - 16384];
}

extern "C" void kernel_launch(void* const* d_in, const int* in_sizes, int n_in,
                              void* d_out, int out_size, void* d_ws, size_t ws_size,
                              hipStream_t stream){
    (void)in_sizes; (void)n_in; (void)out_size; (void)ws_size;
    const float* Y       = (const float*)d_in[0];
    const float* raw     = (const float*)d_in[1];
    const float* kern    = (const float*)d_in[2];
    const float* readout = (const float*)d_in[3];
    const float* K       = (const float*)d_in[4];
    const float* bias    = (const float*)d_in[5];
    float* out = (float*)d_out;
    float* ws  = (float*)d_ws;

    float* invKb    = ws;                      // 35360 blocked invK
    float* Sblk     = invKb + NBLKF;           // 35360 blocked X^T of K'
    float* W        = Sblk + NBLKF;            // 1,638,400
    float* muA      = W + 1638400;             // 16384
    float* muB      = muA + 16384;             // 16384
    float* lambd    = muB + 16384;             // 204800
    float* diagA    = lambd + 204800;          // 16384
    float* diagB    = diagA + 16384;           // 16384
    float* gradPart = diagB + 16384;           // 131072 (8 chunks x 64 x 256)
    float* w2lPart  = gradPart + 131072;       // 131072
    float* scal     = w2lPart + 131072;        // 64
    float* kt       = scal + 64;               // 500,000

    k_zero<<<64, 256, 0, stream>>>(muA, scal);
    k_transpose<<<(NNEUR*NTAU*NNEUR + 255)/256, 256, 0, stream>>>(kern, kt);
    k_conv_weights<<<NTRIAL*NNEUR, 256, 0, stream>>>(raw, kt, readout, W);

    // one-time: X = chol(K')^-1 blocked/transposed, logdet(K'); then invKb = X^T X
    k_fact<0><<<1, 512, 0, stream>>>(K, nullptr, nullptr, nullptr, nullptr,
                                     nullptr, nullptr, Sblk, scal, 0, 0);
    k_syrk<<<NSLOT, 256, 0, stream>>>(Sblk, invKb);

    for (int it = 0; it < 5; ++it){
        const float* muI = (it & 1) ? muB : muA;
        float*       muO = (it & 1) ? muA : muB;
        const float* dI  = (it & 1) ? diagB : diagA;
        float*       dO  = (it & 1) ? diagA : diagB;
        int it0 = (it == 0) ? 1 : 0;
        int it4 = (it == 4) ? 1 : 0;
        k_grad2<<<64, 256, 0, stream>>>(W, Y, bias, muI, dI, gradPart, w2lPart,
                                        lambd, scal, it0, it4);
        k_fact<1><<<NMAT, 512, 0, stream>>>(nullptr, invKb, gradPart, w2lPart, muI,
                                            muO, dO, nullptr, scal, it4, it);
    }
    k_loss<<<1, 1, 0, stream>>>(scal, out + 16384 + 204800);
    k_gather<<<864, 256, 0, stream>>>(muB, lambd, out);
}

// Round 6
// 1592.060 us; speedup vs baseline: 1.0645x; 1.0645x over previous
//
#include <hip/hip_runtime.h>

#define NTRIAL 8
#define NNEUR 100
#define NTT 256
#define NT_FULL 300
#define NTAU 50
#define NLAT 8
#define NPAD 44
#define LRATE 0.2f
#define JITTER 0.001f
#define NMAT 64            // NTRIAL*NLAT batched 256x256 systems
#define NSLOT 136          // 16*17/2 lower 16x16 blocks
#define SPITCH 260
#define NBLKF4 8840        // NSLOT*65 float4

__device__ __forceinline__ int bslot(int I, int J){ return ((I*(I+1))>>1) + J; }
__device__ __forceinline__ int rcs(int i, int j){
    return i*16 + ((((j>>2) + (i>>2))&3)<<2) + (j&3);
}
__device__ __forceinline__ int rc4(int i, int q){ return i*4 + ((q + (i>>2))&3); }
__device__ __forceinline__ int f4idx(int I, int J, int i, int q){
    return bslot(I,J)*65 + rc4(i,q);
}
__device__ __forceinline__ float4 f4fma(float s, float4 v, float4 a){
    a.x += s*v.x; a.y += s*v.y; a.z += s*v.z; a.w += s*v.w; return a;
}
__device__ __forceinline__ void sdecode(int s, int& I, int& J){
    int i = (int)floorf((sqrtf(8.f*(float)s + 1.f) - 1.f)*0.5f);
    while (((i+1)*(i+2))>>1 <= s) ++i;
    while ((i*(i+1))>>1 > s) --i;
    I = i; J = s - ((i*(i+1))>>1);
}
#define DOT4(u,v) (u.x*v.x + u.y*v.y + u.z*v.z + u.w*v.w)

// acc += rowsA(ti..+3).rowsB(tj..+3) over 16-wide dots (both row-chunk-swizzled tiles)
__device__ __forceinline__ void gemmRR(const float4* A, int baseA, const float4* B, int baseB,
                                       int ti, int tj, float acc[4][4]){
    #pragma unroll
    for (int kc = 0; kc < 4; ++kc){
        float4 a0 = A[baseA + rc4(ti+0,kc)];
        float4 a1 = A[baseA + rc4(ti+1,kc)];
        float4 a2 = A[baseA + rc4(ti+2,kc)];
        float4 a3 = A[baseA + rc4(ti+3,kc)];
        float4 b0 = B[baseB + rc4(tj+0,kc)];
        float4 b1 = B[baseB + rc4(tj+1,kc)];
        float4 b2 = B[baseB + rc4(tj+2,kc)];
        float4 b3 = B[baseB + rc4(tj+3,kc)];
        acc[0][0]+=DOT4(a0,b0); acc[0][1]+=DOT4(a0,b1); acc[0][2]+=DOT4(a0,b2); acc[0][3]+=DOT4(a0,b3);
        acc[1][0]+=DOT4(a1,b0); acc[1][1]+=DOT4(a1,b1); acc[1][2]+=DOT4(a1,b2); acc[1][3]+=DOT4(a1,b3);
        acc[2][0]+=DOT4(a2,b0); acc[2][1]+=DOT4(a2,b1); acc[2][2]+=DOT4(a2,b2); acc[2][3]+=DOT4(a2,b3);
        acc[3][0]+=DOT4(a3,b0); acc[3][1]+=DOT4(a3,b1); acc[3][2]+=DOT4(a3,b2); acc[3][3]+=DOT4(a3,b3);
    }
}

// ---------------- init ----------------
__global__ void k_zero(float* mu, float* v, float* scal){
    int i = blockIdx.x*256 + threadIdx.x;
    if (i < 16384){ mu[i] = 0.f; v[i] = 0.f; }
    if (i < 64) scal[i] = 0.f;
}

__global__ void k_transpose(const float* __restrict__ kern, float* __restrict__ kt){
    int idx = blockIdx.x*256 + threadIdx.x;
    if (idx >= NNEUR*NTAU*NNEUR) return;
    int i = idx/(NTAU*NNEUR); int rem = idx%(NTAU*NNEUR);
    int tau = rem/NNEUR; int j = rem%NNEUR;
    kt[((size_t)i*NNEUR + j)*NTAU + tau] = kern[idx];
}

// ---------------- conv + readout contraction ----------------
__global__ __launch_bounds__(256) void k_conv_weights(const float* __restrict__ raw,
                                                      const float* __restrict__ kt,
                                                      const float* __restrict__ readout,
                                                      float* __restrict__ W){
    int b = blockIdx.x; int m = b / NNEUR; int j = b % NNEUR; int t = threadIdx.x;
    __shared__ float ro[NNEUR*NLAT];
    __shared__ float raw_s[10][NT_FULL];
    __shared__ float kern_s[10][NTAU];
    for (int idx = t; idx < NNEUR*NLAT; idx += 256) ro[idx] = readout[idx];
    float acc[NLAT];
    #pragma unroll
    for (int l = 0; l < NLAT; ++l) acc[l] = 0.f;
    int tmax = min(NTAU, t + NPAD);
    for (int c = 0; c < 10; ++c){
        __syncthreads();
        for (int idx = t; idx < 10*NT_FULL; idx += 256){
            int ii = idx / NT_FULL, tt = idx % NT_FULL;
            raw_s[ii][tt] = raw[((size_t)m*NNEUR + c*10 + ii)*NT_FULL + tt];
        }
        for (int idx = t; idx < 10*NTAU; idx += 256){
            int ii = idx / NTAU, tau = idx % NTAU;
            kern_s[ii][tau] = kt[((size_t)(c*10 + ii)*NNEUR + j)*NTAU + tau];
        }
        __syncthreads();
        for (int ii = 0; ii < 10; ++ii){
            float g = 0.f;
            const float* kr = kern_s[ii];
            const float* rr = raw_s[ii];
            for (int tau = 1; tau <= tmax; ++tau) g += kr[tau-1] * rr[t + NPAD - tau];
            if (fabsf(g) < 1e-5f) g = 0.f;   // ZERO_THRESH before readout contraction
            const float* rop = &ro[(c*10 + ii)*NLAT];
            #pragma unroll
            for (int l = 0; l < NLAT; ++l) acc[l] += rop[l]*g;
        }
    }
    #pragma unroll
    for (int l = 0; l < NLAT; ++l) W[(((size_t)b)*NLAT + l)*NTT + t] = acc[l];
}

// ---------------- lambda / grad-partials / w2l-partials (reads W exactly once) ----------------
__global__ __launch_bounds__(256) void k_grad2(const float* __restrict__ W, const float* __restrict__ Y,
                                               const float* __restrict__ bias_p,
                                               const float* __restrict__ muIn, const float* __restrict__ diagIn,
                                               float* __restrict__ gradPart, float* __restrict__ w2lPart,
                                               float* __restrict__ lambd, float* __restrict__ scal,
                                               int it0, int it4){
    int blk = blockIdx.x; int m = blk >> 3; int chunk = blk & 7;
    int n0 = chunk*12 + (chunk < 4 ? chunk : 4);
    int cnt = 12 + (chunk < 4 ? 1 : 0);
    int t = threadIdx.x;
    __shared__ float r1[256], r2[256];
    float mul[NLAT], dhl[NLAT];
    #pragma unroll
    for (int l = 0; l < NLAT; ++l){
        mul[l] = muIn[((size_t)(m*NLAT + l))*NTT + t];
        dhl[l] = it0 ? (1.0f + JITTER) : (-diagIn[((size_t)(m*NLAT + l))*NTT + t]);
    }
    float bias = bias_p[0];
    float ga[NLAT], wa[NLAT];
    #pragma unroll
    for (int l = 0; l < NLAT; ++l){ ga[l] = 0.f; wa[l] = 0.f; }
    float yl = 0.f, ls = 0.f;
    for (int n = n0; n < n0 + cnt; ++n){
        size_t base = (((size_t)(m*NNEUR + n))*NLAT)*NTT + t;
        float wl[NLAT];
        float ll = bias, q = 0.f;
        #pragma unroll
        for (int l = 0; l < NLAT; ++l){
            float w = W[base + (size_t)l*NTT];
            wl[l] = w;
            ll += w * mul[l];
            q  += w * w * dhl[l];
        }
        float lam = expf(ll + 0.5f*q);
        float yv = Y[((size_t)(m*NNEUR + n))*NTT + t];
        float d = yv - lam;
        #pragma unroll
        for (int l = 0; l < NLAT; ++l){ ga[l] += wl[l]*d; wa[l] += wl[l]*wl[l]*lam; }
        if (it4){
            lambd[((size_t)(m*NNEUR + n))*NTT + t] = lam;
            yl += yv * ll; ls += lam;
        }
    }
    #pragma unroll
    for (int l = 0; l < NLAT; ++l){
        gradPart[((size_t)((chunk<<6) + m*NLAT + l))*NTT + t] = ga[l];
        w2lPart [((size_t)((chunk<<6) + m*NLAT + l))*NTT + t] = wa[l];
    }
    if (it4){
        r1[t] = yl; r2[t] = ls;
        __syncthreads();
        for (int s = 128; s > 0; s >>= 1){ if (t < s){ r1[t]+=r1[t+s]; r2[t]+=r2[t+s]; } __syncthreads(); }
        if (t == 0){ atomicAdd(&scal[0], r1[0]); atomicAdd(&scal[1], r2[0]); }
    }
}

// trsm tile: compute C_{r} col-tile j (cols 16j..16j+15) of C = L^-1 (D^1/2 K').
// Pair-split over K range (half 0/1), shfl_xor(16) combine, half0 applies Xinv_r,
// accumulates colnorms, writes C to global.
__device__ __forceinline__ void trsm_tile(
    int r, int j, int half,
    const float* __restrict__ Kg, float* __restrict__ Cb,
    const float4* P4, const float4* XinvL4,
    const float* dsc, float* colnorm,
    int gt, int ti, int tj, int lanebase)
{
    float4 t0 = make_float4(0.f,0.f,0.f,0.f), t1 = t0, t2 = t0, t3 = t0;
    const float4* C4 = (const float4*)Cb;
    const int cchunk = (j<<2) + (tj>>2);
    for (int K = half; K < r; K += 2){
        const int ab = bslot(r,K)*65;
        #pragma unroll
        for (int kc = 0; kc < 4; ++kc){
            float4 a0 = P4[ab + rc4(ti+0,kc)];
            float4 a1 = P4[ab + rc4(ti+1,kc)];
            float4 a2 = P4[ab + rc4(ti+2,kc)];
            float4 a3 = P4[ab + rc4(ti+3,kc)];
            const int cr = (((K<<4) + (kc<<2))<<6) + cchunk;
            float4 c0 = C4[cr], c1 = C4[cr+64], c2 = C4[cr+128], c3 = C4[cr+192];
            t0 = f4fma(-a0.x,c0, f4fma(-a0.y,c1, f4fma(-a0.z,c2, f4fma(-a0.w,c3, t0))));
            t1 = f4fma(-a1.x,c0, f4fma(-a1.y,c1, f4fma(-a1.z,c2, f4fma(-a1.w,c3, t1))));
            t2 = f4fma(-a2.x,c0, f4fma(-a2.y,c1, f4fma(-a2.z,c2, f4fma(-a2.w,c3, t2))));
            t3 = f4fma(-a3.x,c0, f4fma(-a3.y,c1, f4fma(-a3.z,c2, f4fma(-a3.w,c3, t3))));
        }
    }
    if (half == 0){
        const float4* K4 = (const float4*)Kg;
        #pragma unroll
        for (int a = 0; a < 4; ++a){
            int row = (r<<4) + ti + a;
            float4 kv = K4[row*64 + cchunk];
            int dcol = row - ((j<<4) + tj);
            if (dcol >= 0 && dcol < 4) ((float*)&kv)[dcol] += JITTER;
            float s = dsc[row];
            if      (a == 0) t0 = f4fma(s, kv, t0);
            else if (a == 1) t1 = f4fma(s, kv, t1);
            else if (a == 2) t2 = f4fma(s, kv, t2);
            else             t3 = f4fma(s, kv, t3);
        }
    }
    t0.x += __shfl_xor(t0.x,16,64); t0.y += __shfl_xor(t0.y,16,64); t0.z += __shfl_xor(t0.z,16,64); t0.w += __shfl_xor(t0.w,16,64);
    t1.x += __shfl_xor(t1.x,16,64); t1.y += __shfl_xor(t1.y,16,64); t1.z += __shfl_xor(t1.z,16,64); t1.w += __shfl_xor(t1.w,16,64);
    t2.x += __shfl_xor(t2.x,16,64); t2.y += __shfl_xor(t2.y,16,64); t2.z += __shfl_xor(t2.z,16,64); t2.w += __shfl_xor(t2.w,16,64);
    t3.x += __shfl_xor(t3.x,16,64); t3.y += __shfl_xor(t3.y,16,64); t3.z += __shfl_xor(t3.z,16,64); t3.w += __shfl_xor(t3.w,16,64);
    if (half) return;
    // apply Xinv_r:  out[i][c] = sum_k Xinv[i][k] T[k][c]
    const float4* XB = XinvL4 + (r&1)*65;
    float4 o0 = make_float4(0.f,0.f,0.f,0.f), o1 = o0, o2 = o0, o3 = o0;
    #pragma unroll
    for (int kc = 0; kc < 4; ++kc){
        int src = lanebase + (kc<<2) + (gt&3);
        float4 v0, v1, v2, v3;
        v0.x=__shfl(t0.x,src,64); v0.y=__shfl(t0.y,src,64); v0.z=__shfl(t0.z,src,64); v0.w=__shfl(t0.w,src,64);
        v1.x=__shfl(t1.x,src,64); v1.y=__shfl(t1.y,src,64); v1.z=__shfl(t1.z,src,64); v1.w=__shfl(t1.w,src,64);
        v2.x=__shfl(t2.x,src,64); v2.y=__shfl(t2.y,src,64); v2.z=__shfl(t2.z,src,64); v2.w=__shfl(t2.w,src,64);
        v3.x=__shfl(t3.x,src,64); v3.y=__shfl(t3.y,src,64); v3.z=__shfl(t3.z,src,64); v3.w=__shfl(t3.w,src,64);
        float4 x0 = XB[rc4(ti+0,kc)], x1 = XB[rc4(ti+1,kc)], x2 = XB[rc4(ti+2,kc)], x3 = XB[rc4(ti+3,kc)];
        o0 = f4fma(x0.x,v0, f4fma(x0.y,v1, f4fma(x0.z,v2, f4fma(x0.w,v3, o0))));
        o1 = f4fma(x1.x,v0, f4fma(x1.y,v1, f4fma(x1.z,v2, f4fma(x1.w,v3, o1))));
        o2 = f4fma(x2.x,v0, f4fma(x2.y,v1, f4fma(x2.z,v2, f4fma(x2.w,v3, o2))));
        o3 = f4fma(x3.x,v0, f4fma(x3.y,v1, f4fma(x3.z,v2, f4fma(x3.w,v3, o3))));
    }
    float4 cn;
    cn.x = o0.x*o0.x + o1.x*o1.x + o2.x*o2.x + o3.x*o3.x;
    cn.y = o0.y*o0.y + o1.y*o1.y + o2.y*o2.y + o3.y*o3.y;
    cn.z = o0.z*o0.z + o1.z*o1.z + o2.z*o2.z + o3.z*o3.z;
    cn.w = o0.w*o0.w + o1.w*o1.w + o2.w*o2.w + o3.w*o3.w;
    cn.x += __shfl_xor(cn.x,4,64); cn.y += __shfl_xor(cn.y,4,64); cn.z += __shfl_xor(cn.z,4,64); cn.w += __shfl_xor(cn.w,4,64);
    cn.x += __shfl_xor(cn.x,8,64); cn.y += __shfl_xor(cn.y,8,64); cn.z += __shfl_xor(cn.z,8,64); cn.w += __shfl_xor(cn.w,8,64);
    if (gt < 4){
        int cb = (j<<4) + (gt<<2);
        colnorm[cb+0] += cn.x; colnorm[cb+1] += cn.y; colnorm[cb+2] += cn.z; colnorm[cb+3] += cn.w;
    }
    float4* C4w = (float4*)Cb;
    const int wr = (((r<<4)+ti)<<6) + cchunk;
    C4w[wr]       = o0;
    C4w[wr + 64]  = o1;
    C4w[wr + 128] = o2;
    C4w[wr + 192] = o3;
}

// ============ fused: M=I+D^1/2 K' D^1/2 build + blocked chol + streamed trsm + solve ============
__global__ __launch_bounds__(512) void k_fact2(
    const float* __restrict__ Kg,
    const float* __restrict__ gradPart,
    const float* __restrict__ w2lPart,
    const float* __restrict__ muIn,
    const float* __restrict__ vIn,
    float* __restrict__ muOut,
    float* __restrict__ vOut,
    float* __restrict__ diagOut,
    float* __restrict__ Cbuf,
    float* __restrict__ scal,
    int it4, int itSlot)
{
    __shared__ float4 P4[NBLKF4];        // 141,440 B blocked lower-tri M/L
    __shared__ float4 XinvL4[130];       //   2,080 B double-buffered Xinv_pp
    __shared__ float dlog[256];          //   chol diag values (reused as cg in epilogue)
    __shared__ float idg[16];
    __shared__ __align__(16) float gs[256];
    __shared__ float w2ls[256], dsc[256], colnorm[256];
    __shared__ float scr[1024];
    __shared__ float sldM;
    const int t = threadIdx.x;
    const int b = blockIdx.x;
    const int g = t>>4, gt = t&15;
    const int ti = (gt>>2)<<2, tj = (gt&3)<<2;
    const int lanebase = t & 48;
    float* Cb = Cbuf + (size_t)b*65536;

    // ---------------- prologue ----------------
    float muin_r = 0.f, vin_r = 0.f;
    if (t < 256){
        float gg = 0.f, ww = 0.f;
        #pragma unroll
        for (int c = 0; c < 8; ++c){
            gg += gradPart[(((size_t)((c<<6) + b))<<8) + t];
            ww += w2lPart [(((size_t)((c<<6) + b))<<8) + t];
        }
        muin_r = muIn[((size_t)b<<8) + t];
        vin_r  = vIn [((size_t)b<<8) + t];
        w2ls[t] = ww; dsc[t] = sqrtf(ww);
        gs[t] = gg - vin_r;              // grad = sum_n w(Y-lam) - invK*mu
        colnorm[t] = 0.f;
    }
    __syncthreads();
    // M build: M_ij = delta_ij + d_i d_j (K_ij + jitter delta_ij)
    {
        const float4* K4 = (const float4*)Kg;
        for (int s = g; s < NSLOT; s += 32){
            int I, J; sdecode(s, I, J);
            int row = (I<<4) + gt;
            float dr = dsc[row];
            #pragma unroll
            for (int q = 0; q < 4; ++q){
                float4 kv = K4[row*64 + (J<<2) + q];
                int cb = (J<<4) + (q<<2);
                kv.x *= dr*dsc[cb+0]; kv.y *= dr*dsc[cb+1]; kv.z *= dr*dsc[cb+2]; kv.w *= dr*dsc[cb+3];
                if (I == J){
                    int dcol = gt - (q<<2);
                    if (dcol >= 0 && dcol < 4) ((float*)&kv)[dcol] += 1.f + dr*dr*JITTER;
                }
                P4[s*65 + rc4(gt,q)] = kv;
            }
        }
    }
    __syncthreads();

    // ---------------- blocked chol(M) + streamed trsm ----------------
    for (int p = 0; p <= 16; ++p){
        if (p == 16){
            // final trsm of C_15: all 32 groups paired
            trsm_tile(15, g>>1, g&1, Kg, Cb, P4, XinvL4, dsc, colnorm, gt, ti, tj, lanebase);
            __syncthreads();
            break;
        }
        // ======= PHASE A =======
        if (g == 31){
            float x[16];
            if (p > 0){
                float acc[4][4];
                #pragma unroll
                for (int aa=0;aa<4;++aa){acc[aa][0]=0;acc[aa][1]=0;acc[aa][2]=0;acc[aa][3]=0;}
                gemmRR(P4, bslot(p,p-1)*65, P4, bslot(p,p-1)*65, ti, tj, acc);
                #pragma unroll
                for (int aa = 0; aa < 4; ++aa){
                    int oi = f4idx(p,p,ti+aa,tj>>2);
                    float4 c = P4[oi];
                    c.x-=acc[aa][0]; c.y-=acc[aa][1]; c.z-=acc[aa][2]; c.w-=acc[aa][3];
                    P4[oi] = c;
                }
            }
            #pragma unroll
            for (int q = 0; q < 4; ++q){
                float4 v = P4[f4idx(p,p,gt,q)];
                x[4*q]=v.x; x[4*q+1]=v.y; x[4*q+2]=v.z; x[4*q+3]=v.w;
            }
            const int i = gt;
            #pragma unroll
            for (int k = 0; k < 16; ++k){
                float piv = __shfl(x[k], lanebase + k, 64);
                float d = sqrtf(piv);
                float dinv = 1.f/d;
                float lik = (i == k) ? d : x[k]*dinv;
                if (i >= k) x[k] = lik;
                #pragma unroll
                for (int c = k+1; c < 16; ++c){
                    float lck = __shfl(x[k], lanebase + c, 64);
                    if (i >= c) x[c] -= lik*lck;
                }
                if (i == k){ idg[k] = dinv; dlog[p*16+k] = d; }
            }
            float col[16];
            #pragma unroll
            for (int ii = 0; ii < 16; ++ii){
                float s = 0.f;
                #pragma unroll
                for (int k = 0; k < 16; ++k){
                    if (k < ii){
                        float lik = __shfl(x[k], lanebase + ii, 64);
                        s += lik * col[k];
                    }
                }
                float v = ((gt == ii) ? 1.f : -s) * idg[ii];
                col[ii] = (gt <= ii) ? v : 0.f;
            }
            float* XL = (float*)(XinvL4 + (p&1)*65);
            #pragma unroll
            for (int ii = 0; ii < 16; ++ii) XL[rcs(ii, gt)] = col[ii];
        } else if (g < 28){
            // unified task list: [16 trsm-halves of C_{p-1} tiles 0..7] + trailing tiles
            int ntrsm = (p >= 1) ? 16 : 0;
            int m16 = 16 - p;
            int ntrail = (p >= 1) ? ((m16*(m16+1))>>1) - 1 : 0;
            for (int id = g; id < ntrsm + ntrail; id += 28){
                if (id < ntrsm){
                    trsm_tile(p-1, id>>1, id&1, Kg, Cb, P4, XinvL4, dsc, colnorm, gt, ti, tj, lanebase);
                } else {
                    int q = id - ntrsm + 1;
                    int di, dj; sdecode(q, di, dj);
                    int I = p + di, J = p + dj;
                    float acc[4][4];
                    #pragma unroll
                    for (int aa=0;aa<4;++aa){acc[aa][0]=0;acc[aa][1]=0;acc[aa][2]=0;acc[aa][3]=0;}
                    gemmRR(P4, bslot(I,p-1)*65, P4, bslot(J,p-1)*65, ti, tj, acc);
                    #pragma unroll
                    for (int aa = 0; aa < 4; ++aa){
                        int oi = f4idx(I,J,ti+aa,tj>>2);
                        float4 c = P4[oi];
                        c.x-=acc[aa][0]; c.y-=acc[aa][1]; c.z-=acc[aa][2]; c.w-=acc[aa][3];
                        P4[oi] = c;
                    }
                }
            }
        }
        __syncthreads();
        // ======= PHASE B =======
        if (p >= 1 && g < 16){
            trsm_tile(p-1, 8 + (g>>1), g&1, Kg, Cb, P4, XinvL4, dsc, colnorm, gt, ti, tj, lanebase);
        } else if (g >= 16 && g < 31){
            for (int id = g - 16; id < 15 - p; id += 15){
                int I = p + 1 + id;
                float acc[4][4];
                #pragma unroll
                for (int aa=0;aa<4;++aa){acc[aa][0]=0;acc[aa][1]=0;acc[aa][2]=0;acc[aa][3]=0;}
                gemmRR(P4, bslot(I,p)*65, XinvL4, (p&1)*65, ti, tj, acc);
                #pragma unroll
                for (int aa = 0; aa < 4; ++aa)
                    P4[f4idx(I,p,ti+aa,tj>>2)] =
                        make_float4(acc[aa][0],acc[aa][1],acc[aa][2],acc[aa][3]);
            }
        }
        __syncthreads();
    }

    // ---------------- epilogue ----------------
    // logdet(M)
    scr[t] = (t < 256) ? 2.f*logf(dlog[t]) : 0.f;
    __syncthreads();
    for (int s = 256; s > 0; s >>= 1){ if (t < s) scr[t] += scr[t+s]; __syncthreads(); }
    if (t == 0) sldM = scr[0];
    __syncthreads();
    // h = K g  (K symmetric, coalesced column access)
    {
        int t2 = t & 255, hf = t >> 8;
        float acc = 0.f;
        const float* Kr = Kg + (size_t)hf*128*256 + t2;
        for (int u = 0; u < 128; ++u) acc += gs[hf*128 + u]*Kr[(size_t)u*256];
        scr[(hf<<8) + t2] = acc;
    }
    __syncthreads();
    float* hv = (float*)XinvL4;
    if (t < 256) hv[t] = scr[t] + scr[256+t];
    // cg = C g (rows)
    {
        int t2 = t & 255, hf = t >> 8;
        const float4* Crow = ((const float4*)Cb) + (size_t)t2*64;
        const float4* g4 = (const float4*)gs;
        float acc = 0.f;
        for (int q = hf*32; q < hf*32 + 32; ++q){
            float4 c = Crow[q], gq = g4[q];
            acc += c.x*gq.x + c.y*gq.y + c.z*gq.z + c.w*gq.w;
        }
        scr[512 + (hf<<8) + t2] = acc;
    }
    __syncthreads();
    if (t < 256) dlog[t] = scr[512+t] + scr[768+t];    // cg
    __syncthreads();
    // ct = C^T cg (coalesced)
    {
        int t2 = t & 255, hf = t >> 8;
        float acc = 0.f;
        const float* Cp = Cb + (size_t)hf*128*256 + t2;
        for (int i = 0; i < 128; ++i) acc += Cp[(size_t)i*256]*dlog[hf*128 + i];
        scr[(hf<<8) + t2] = acc;
    }
    __syncthreads();
    if (t < 256){
        float ct = scr[t] + scr[256+t];
        float uval = hv[t] + JITTER*gs[t] - ct;        // u = A^-1 grad
        float diagv = Kg[(size_t)t*257] + JITTER - colnorm[t];
        diagOut[((size_t)b<<8) + t] = diagv;
        muOut[((size_t)b<<8) + t] = muin_r + LRATE*uval;
        vOut [((size_t)b<<8) + t] = vin_r + LRATE*(gs[t] - w2ls[t]*uval);
        scr[t]     = w2ls[t]*diagv;
        scr[256+t] = it4 ? (vin_r*muin_r) : 0.f;
    }
    __syncthreads();
    for (int s = 128; s > 0; s >>= 1){
        if (t < s){ scr[t] += scr[t+s]; scr[256+t] += scr[256+t+s]; }
        __syncthreads();
    }
    if (t == 0){
        atomicAdd(&scal[8 + itSlot],  scr[0] - 256.f);   // trace(invK * hinv)
        atomicAdd(&scal[24 + itSlot], -sldM);            // logabsdet(iKh) = -logdet(M)
        if (it4) atomicAdd(&scal[2], scr[256]);          // mu.invK.mu
    }
}

__global__ void k_loss(const float* __restrict__ scal, float* __restrict__ out_loss){
    // loss = sum(Y*ll) - sum(lam) - 0.5*muKmu - 0.5*trace + 0.5*logabs - nt
    out_loss[0] = scal[0] - scal[1] - 0.5f*scal[2] - 0.5f*scal[8+3] + 0.5f*scal[24+3] - 256.f;
}

__global__ void k_gather(const float* __restrict__ mu, const float* __restrict__ lambd, float* __restrict__ out){
    int idx = blockIdx.x*256 + threadIdx.x;
    if (idx < 16384) out[idx] = mu[idx];
    else if (idx < 16384 + 204800) out[idx] = lambd[idx - 16384];
}

extern "C" void kernel_launch(void* const* d_in, const int* in_sizes, int n_in,
                              void* d_out, int out_size, void* d_ws, size_t ws_size,
                              hipStream_t stream){
    (void)in_sizes; (void)n_in; (void)out_size; (void)ws_size;
    const float* Y       = (const float*)d_in[0];
    const float* raw     = (const float*)d_in[1];
    const float* kern    = (const float*)d_in[2];
    const float* readout = (const float*)d_in[3];
    const float* K       = (const float*)d_in[4];
    const float* bias    = (const float*)d_in[5];
    float* out = (float*)d_out;
    float* ws  = (float*)d_ws;

    float* W        = ws;                      // 1,638,400
    float* Cbuf     = W + 1638400;             // 4,194,304 (64 x 256 x 256)
    float* muA      = Cbuf + 4194304;          // 16384
    float* muB      = muA + 16384;
    float* vA       = muB + 16384;
    float* vB       = vA + 16384;
    float* diagA    = vB + 16384;
    float* diagB    = diagA + 16384;
    float* gradPart = diagB + 16384;           // 131072
    float* w2lPart  = gradPart + 131072;       // 131072
    float* lambd    = w2lPart + 131072;        // 204800
    float* scal     = lambd + 204800;          // 64
    float* kt       = scal + 64;               // 500,000

    k_zero<<<64, 256, 0, stream>>>(muA, vA, scal);
    k_transpose<<<(NNEUR*NTAU*NNEUR + 255)/256, 256, 0, stream>>>(kern, kt);
    k_conv_weights<<<NTRIAL*NNEUR, 256, 0, stream>>>(raw, kt, readout, W);

    for (int it = 0; it < 5; ++it){
        const float* muI = (it & 1) ? muB : muA;
        float*       muO = (it & 1) ? muA : muB;
        const float* vI  = (it & 1) ? vB : vA;
        float*       vO  = (it & 1) ? vA : vB;
        const float* dI  = (it & 1) ? diagB : diagA;
        float*       dO  = (it & 1) ? diagA : diagB;
        int it0 = (it == 0) ? 1 : 0;
        int it4 = (it == 4) ? 1 : 0;
        k_grad2<<<64, 256, 0, stream>>>(W, Y, bias, muI, dI, gradPart, w2lPart,
                                        lambd, scal, it0, it4);
        k_fact2<<<NMAT, 512, 0, stream>>>(K, gradPart, w2lPart, muI, vI,
                                          muO, vO, dO, Cbuf, scal, it4, it);
    }
    k_loss<<<1, 1, 0, stream>>>(scal, out + 16384 + 204800);
    k_gather<<<864, 256, 0, stream>>>(muB, lambd, out);
}